// Round 7
// baseline (791.208 us; speedup 1.0000x reference)
//
#include <hip/hip_runtime.h>
#include <hip/hip_bf16.h>
#include <stdint.h>

// ---------------------------------------------------------------------------
// LinearFLHGS: per-group(64) symmetric int4 quant-dequant of x and w, then
// C = x_dq @ w_dq^T.  Round 7: EXACT integer path.  Since values are q*s with
// q in [-8,7] and group size == BK == 64, compute per-K-tile integer dot
// products with mfma_i32_16x16x64_i8 (i32 accum, exact; one MFMA spans the
// whole K-tile per fragment) and apply the f32 scale product sa*sb in a
// per-tile VALU fixup.  Halves LDS+HBM traffic vs bf16 and raises the MFMA
// ceiling 1.9x.  256x256 tile, 8 waves, double-buffered 64KB LDS, both-sides
// XOR swizzle re-derived for 64B rows (chunk ^= (row>>1)&3).
// ---------------------------------------------------------------------------

typedef int   int32x4 __attribute__((ext_vector_type(4)));
typedef float f32x4   __attribute__((ext_vector_type(4)));

// Per-group-of-64 symmetric int4 quant -> i8 codes + transposed f32 scales.
// scale layout: sT[group][row] so GEMM reads 4 consecutive rows as dwordx4.
__global__ void quant_kernel(const float* __restrict__ in,
                             int8_t* __restrict__ qout,
                             float* __restrict__ sT,
                             int total4, int nrows) {
    int nth = gridDim.x * blockDim.x;
    int t0 = blockIdx.x * blockDim.x + threadIdx.x;
    for (int i = t0; i < total4; i += nth) {
        float4 v = ((const float4*)in)[i];
        float amax = fmaxf(fmaxf(fabsf(v.x), fabsf(v.y)),
                           fmaxf(fabsf(v.z), fabsf(v.w)));
        #pragma unroll
        for (int m = 1; m <= 8; m <<= 1)
            amax = fmaxf(amax, __shfl_xor(amax, m, 64));
        float s = fmaxf(amax / 7.0f, 1e-8f);
        int q0 = (int)fminf(fmaxf(rintf(v.x / s), -8.0f), 7.0f);
        int q1 = (int)fminf(fmaxf(rintf(v.y / s), -8.0f), 7.0f);
        int q2 = (int)fminf(fmaxf(rintf(v.z / s), -8.0f), 7.0f);
        int q3 = (int)fminf(fmaxf(rintf(v.w / s), -8.0f), 7.0f);
        uint32_t packed = (uint32_t)(q0 & 255) | ((uint32_t)(q1 & 255) << 8) |
                          ((uint32_t)(q2 & 255) << 16) | ((uint32_t)(q3 & 255) << 24);
        ((uint32_t*)qout)[i] = packed;
        if ((i & 15) == 0) {            // one scale per group of 16 float4s
            int row = i >> 10;          // K/4 = 1024 float4 per row (K=4096)
            int gir = (i & 1023) >> 4;  // group index within row
            sT[(size_t)gir * nrows + row] = s;
        }
    }
}

#define BM 256
#define BN 256

__global__ __launch_bounds__(512, 2) void gemm_kernel(
        const int8_t* __restrict__ A, const int8_t* __restrict__ B,
        const float* __restrict__ sAT, const float* __restrict__ sBT,
        float* __restrict__ C, int M, int N, int K) {
    // [buf][256 rows][64 k] i8 = 16 KB each; total 64 KB
    __shared__ int8_t As[2][256 * 64];
    __shared__ int8_t Bs[2][256 * 64];

    const int NTt = K >> 6;   // 64 K-tiles == 64 scale groups

    int nwg = gridDim.x;
    int bid = blockIdx.x;
    int swz = bid;
    if ((nwg & 7) == 0) {     // bijective XCD swizzle (nwg = 512)
        int cpx = nwg >> 3;
        swz = (bid & 7) * cpx + (bid >> 3);
    }
    int nbn = N / BN;
    int bm = swz / nbn, bn = swz % nbn;

    int tid = threadIdx.x;
    int lane = tid & 63;
    int wid = tid >> 6;       // 0..7
    int wm = wid >> 2;        // 0..1 : 128-row band of A
    int wn = wid & 3;         // 0..3 : 64-col band of B

    const int rowA0 = bm * BM;
    const int colB0 = bn * BN;

    // fragment reads: lane l -> row = base + (l&15), 16B chunk cR = l>>4.
    // swizzle: chunk ^= (row>>1)&3  (row base mult of 16 -> = (rl>>1)&3)
    int rl = lane & 15;
    int cR = lane >> 4;
    int rsw = ((cR ^ ((rl >> 1) & 3)) << 4);   // swizzled byte offset in row
    int rq = cR * 4;                           // acc-reg row base (D-map)

    // staging: inst covers 16 rows; lane -> row R0+(l>>2), chunk l&3;
    // inverse-swizzled global chunk = (l&3) ^ ((row>>1)&3) = (l&3)^((l>>3)&3)
    int sgc = (((lane & 3) ^ ((lane >> 3) & 3)) << 4);

    f32x4 acc[8][4] = {};

    const int8_t* Ag = A + (size_t)rowA0 * K;
    const int8_t* Bg = B + (size_t)colB0 * K;

    auto stage = [&](const int8_t* g0, int8_t* l0, int t) {
        #pragma unroll
        for (int j = 0; j < 2; ++j) {
            int R0 = wid * 32 + j * 16;
            const int8_t* g = g0 + (size_t)(R0 + (lane >> 2)) * K + t * 64 + sgc;
            int8_t* l = l0 + R0 * 64;
            __builtin_amdgcn_global_load_lds(
                (const __attribute__((address_space(1))) void*)g,
                (__attribute__((address_space(3))) void*)l, 16, 0, 0);
        }
    };

    // ---- prologue: stage tiles 0,1; land tile 0 ----
    stage(Ag, As[0], 0); stage(Bg, Bs[0], 0);
    stage(Ag, As[1], 1); stage(Bg, Bs[1], 1);
    asm volatile("s_waitcnt vmcnt(4)" ::: "memory");
    asm volatile("" ::: "memory");
    __builtin_amdgcn_s_barrier();
    asm volatile("" ::: "memory");

    const int32x4 zero = {0, 0, 0, 0};

    for (int t = 0; t < NTt; ++t) {
        int cb = t & 1;

        // ---- all 12 fragment reads (whole K-tile per fragment) ----
        int32x4 bv[4], av0[4], av1[4];
        #pragma unroll
        for (int ni = 0; ni < 4; ++ni)
            bv[ni] = *(const int32x4*)&Bs[cb][(wn * 64 + ni * 16 + rl) * 64 + rsw];
        #pragma unroll
        for (int mi = 0; mi < 4; ++mi)
            av0[mi] = *(const int32x4*)&As[cb][(wm * 128 + mi * 16 + rl) * 64 + rsw];
        #pragma unroll
        for (int mi = 0; mi < 4; ++mi)
            av1[mi] = *(const int32x4*)&As[cb][(wm * 128 + 64 + mi * 16 + rl) * 64 + rsw];

        // ---- scales for this group (issued AFTER stage(t+1): their consume
        //      forces stage(t+1) drained before barrier#2 -> no explicit vmcnt)
        float sbv[4];
        #pragma unroll
        for (int ni = 0; ni < 4; ++ni)
            sbv[ni] = sBT[(size_t)t * N + colB0 + wn * 64 + ni * 16 + rl];
        f32x4 sa0[4];
        #pragma unroll
        for (int mi = 0; mi < 4; ++mi)
            sa0[mi] = *(const f32x4*)&sAT[(size_t)t * M + rowA0 + wm * 128 + mi * 16 + rq];

        // ---- half 0: rows wm*128 .. +63 ----
        #pragma unroll
        for (int mi = 0; mi < 4; ++mi) {
            #pragma unroll
            for (int ni = 0; ni < 4; ++ni) {
                int32x4 iv = __builtin_amdgcn_mfma_i32_16x16x64_i8(
                    av0[mi], bv[ni], zero, 0, 0, 0);
                #pragma unroll
                for (int r = 0; r < 4; ++r)
                    acc[mi][ni][r] += (float)iv[r] * sa0[mi][r] * sbv[ni];
            }
        }

        // scales for half 1 (after half-0 so sa regs recycle; still pre-stage)
        f32x4 sa1[4];
        #pragma unroll
        for (int mi = 0; mi < 4; ++mi)
            sa1[mi] = *(const f32x4*)&sAT[(size_t)t * M + rowA0 + wm * 128 + 64 + mi * 16 + rq];

        // ---- seal all reads of buf[cb], then overwrite it with tile t+2 ----
        asm volatile("s_waitcnt lgkmcnt(0)" ::: "memory");
        asm volatile("" ::: "memory");
        __builtin_amdgcn_s_barrier();
        asm volatile("" ::: "memory");
        if (t + 2 < NTt) { stage(Ag, As[cb], t + 2); stage(Bg, Bs[cb], t + 2); }

        // ---- half 1: rows wm*128+64 .. +127 ----
        #pragma unroll
        for (int mi = 0; mi < 4; ++mi) {
            #pragma unroll
            for (int ni = 0; ni < 4; ++ni) {
                int32x4 iv = __builtin_amdgcn_mfma_i32_16x16x64_i8(
                    av1[mi], bv[ni], zero, 0, 0, 0);
                #pragma unroll
                for (int r = 0; r < 4; ++r)
                    acc[4 + mi][ni][r] += (float)iv[r] * sa1[mi][r] * sbv[ni];
            }
        }

        asm volatile("" ::: "memory");
        __builtin_amdgcn_s_barrier();
        asm volatile("" ::: "memory");
    }

    // ---- epilogue: D map col = lane&15, row = (lane>>4)*4 + reg ----
    int cl = lane & 15;
    #pragma unroll
    for (int mi = 0; mi < 8; ++mi) {
        #pragma unroll
        for (int ni = 0; ni < 4; ++ni) {
            int row = rowA0 + wm * 128 + mi * 16 + rq;
            int col = colB0 + wn * 64 + ni * 16 + cl;
            float* cp = C + (size_t)row * N + col;
            #pragma unroll
            for (int r = 0; r < 4; ++r)
                cp[(size_t)r * N] = acc[mi][ni][r];
        }
    }
}

extern "C" void kernel_launch(void* const* d_in, const int* in_sizes, int n_in,
                              void* d_out, int out_size, void* d_ws, size_t ws_size,
                              hipStream_t stream) {
    const float* x = (const float*)d_in[0];
    const float* w = (const float*)d_in[1];
    float* out = (float*)d_out;

    const int K = 4096;
    const int T = in_sizes[0] / K;   // 8192
    const int O = in_sizes[1] / K;   // 4096

    // workspace layout (51 MB total)
    int8_t* qx  = (int8_t*)d_ws;                                  // T*K i8
    int8_t* qw  = qx + (size_t)T * K;                             // O*K i8
    float*  sxT = (float*)(qw + (size_t)O * K);                   // [K/64][T]
    float*  swT = sxT + (size_t)(K / 64) * T;                     // [K/64][O]

    quant_kernel<<<2048, 256, 0, stream>>>(x, qx, sxT, (T * K) >> 2, T);
    quant_kernel<<<2048, 256, 0, stream>>>(w, qw, swT, (O * K) >> 2, O);

    int nwg = (T / BM) * (O / BN);   // 32*16 = 512
    gemm_kernel<<<nwg, 512, 0, stream>>>(qx, qw, sxT, swT, out, T, O, K);
}

// Round 8
// 349.618 us; speedup vs baseline: 2.2631x; 2.2631x over previous
//
#include <hip/hip_runtime.h>
#include <hip/hip_bf16.h>
#include <stdint.h>

// ---------------------------------------------------------------------------
// LinearFLHGS: per-group(64) symmetric int4 quant-dequant of x and w, then
// C = x_dq @ w_dq^T.  Round 8: exact int4 path, register-pressure-safe.
// 128x128 tile, 4 waves, launch_bounds(256,3) (cap 168 VGPR, 3 blocks/CU).
// Per K-tile (= one scale group of 64): 16x mfma_i32_16x16x64_i8 (exact i32),
// VALU fixup acc += cvt(iv)*sa*sb pipelined depth-2 (iv liveness <= 2,
// sched_barrier(0) fences stop MFMA hoisting -> no spill).  Double-buffered
// 32KB LDS, both-sides XOR swizzle for 64B rows (proven 0 conflicts r7),
// stage(t+1)-drain-via-scale-consume ledger proven in round 7 (absmax 0.031).
// ---------------------------------------------------------------------------

typedef int   int32x4 __attribute__((ext_vector_type(4)));
typedef float f32x4   __attribute__((ext_vector_type(4)));

// Per-group-of-64 symmetric int4 quant -> i8 codes + transposed f32 scales.
__global__ void quant_kernel(const float* __restrict__ in,
                             int8_t* __restrict__ qout,
                             float* __restrict__ sT,
                             int total4, int nrows) {
    int nth = gridDim.x * blockDim.x;
    int t0 = blockIdx.x * blockDim.x + threadIdx.x;
    for (int i = t0; i < total4; i += nth) {
        float4 v = ((const float4*)in)[i];
        float amax = fmaxf(fmaxf(fabsf(v.x), fabsf(v.y)),
                           fmaxf(fabsf(v.z), fabsf(v.w)));
        #pragma unroll
        for (int m = 1; m <= 8; m <<= 1)
            amax = fmaxf(amax, __shfl_xor(amax, m, 64));
        float s = fmaxf(amax / 7.0f, 1e-8f);
        int q0 = (int)fminf(fmaxf(rintf(v.x / s), -8.0f), 7.0f);
        int q1 = (int)fminf(fmaxf(rintf(v.y / s), -8.0f), 7.0f);
        int q2 = (int)fminf(fmaxf(rintf(v.z / s), -8.0f), 7.0f);
        int q3 = (int)fminf(fmaxf(rintf(v.w / s), -8.0f), 7.0f);
        uint32_t packed = (uint32_t)(q0 & 255) | ((uint32_t)(q1 & 255) << 8) |
                          ((uint32_t)(q2 & 255) << 16) | ((uint32_t)(q3 & 255) << 24);
        ((uint32_t*)qout)[i] = packed;
        if ((i & 15) == 0) {            // one scale per group (16 float4s)
            int row = i >> 10;          // K/4 = 1024 float4 per row (K=4096)
            int gir = (i & 1023) >> 4;
            sT[(size_t)gir * nrows + row] = s;
        }
    }
}

#define BM 128
#define BN 128

#define FENCE() asm volatile("" ::: "memory")
#define SB0()   __builtin_amdgcn_sched_barrier(0)

__global__ __launch_bounds__(256, 3) void gemm_kernel(
        const int8_t* __restrict__ A, const int8_t* __restrict__ B,
        const float* __restrict__ sAT, const float* __restrict__ sBT,
        float* __restrict__ C, int M, int N, int K) {
    // [buf][128 rows][64 k] i8 = 8 KB each; total 32 KB
    __shared__ int8_t As[2][128 * 64];
    __shared__ int8_t Bs[2][128 * 64];

    const int NTt = K >> 6;   // 64 K-tiles == scale groups

    int nwg = gridDim.x;
    int bid = blockIdx.x;
    int swz = bid;
    if ((nwg & 7) == 0) {     // bijective XCD swizzle (nwg = 2048)
        int cpx = nwg >> 3;
        swz = (bid & 7) * cpx + (bid >> 3);
    }
    int nbn = N / BN;
    int bm = swz / nbn, bn = swz % nbn;

    int tid = threadIdx.x;
    int lane = tid & 63;
    int wid = tid >> 6;       // 0..3
    int wr = wid >> 1;        // 0..1 : 64-row band of A
    int wc = wid & 1;         // 0..1 : 64-col band of B

    const int rowA0 = bm * BM;
    const int colB0 = bn * BN;

    // fragment reads: lane l -> row rl = l&15, 16B logical chunk cR = l>>4;
    // physical chunk = cR ^ ((rl>>1)&3)  (64B rows, 4 chunks)
    int rl = lane & 15;
    int cR = lane >> 4;
    int rsw = (cR ^ ((rl >> 1) & 3)) << 4;
    int rq = cR * 4;          // acc-reg row base (D map)

    // staging: inst covers 16 rows; lane -> row R0+(l>>2), phys chunk l&3;
    // inverse-swizzled global logical chunk = (l&3) ^ ((l>>3)&3)
    int sgc = ((lane & 3) ^ ((lane >> 3) & 3)) << 4;

    f32x4 acc[4][4] = {};

    const int8_t* Ag = A + (size_t)rowA0 * K;
    const int8_t* Bg = B + (size_t)colB0 * K;

    auto stage = [&](const int8_t* g0, int8_t* l0, int t) {
        #pragma unroll
        for (int j = 0; j < 2; ++j) {
            int R0 = wid * 32 + j * 16;
            const int8_t* g = g0 + (size_t)(R0 + (lane >> 2)) * K + t * 64 + sgc;
            int8_t* l = l0 + R0 * 64;
            __builtin_amdgcn_global_load_lds(
                (const __attribute__((address_space(1))) void*)g,
                (__attribute__((address_space(3))) void*)l, 16, 0, 0);
        }
    };

    // ---- prologue: stage tiles 0,1; land tile 0 ----
    stage(Ag, As[0], 0); stage(Bg, Bs[0], 0);
    stage(Ag, As[1], 1); stage(Bg, Bs[1], 1);
    asm volatile("s_waitcnt vmcnt(4)" ::: "memory");
    FENCE(); __builtin_amdgcn_s_barrier(); FENCE();

    const int32x4 zero = {0, 0, 0, 0};

    for (int t = 0; t < NTt; ++t) {
        int cb = t & 1;

        // ---- 8 fragment reads (whole K-tile per fragment) ----
        int32x4 av[4], bv[4];
        #pragma unroll
        for (int ni = 0; ni < 4; ++ni)
            bv[ni] = *(const int32x4*)&Bs[cb][(wc * 64 + ni * 16 + rl) * 64 + rsw];
        #pragma unroll
        for (int mi = 0; mi < 4; ++mi)
            av[mi] = *(const int32x4*)&As[cb][(wr * 64 + mi * 16 + rl) * 64 + rsw];

        // ---- scales (global; consume forces stage(t+1) drain, r7 ledger) ----
        float sb_s[4];
        #pragma unroll
        for (int ni = 0; ni < 4; ++ni)
            sb_s[ni] = sBT[(size_t)t * N + colB0 + wc * 64 + ni * 16 + rl];
        f32x4 sa[4];
        #pragma unroll
        for (int mi = 0; mi < 4; ++mi)
            sa[mi] = *(const f32x4*)&sAT[(size_t)t * M + rowA0 + wr * 64 + mi * 16 + rq];

        // ---- half A (mi=0,1): depth-2 mfma->fixup pipeline ----
        #pragma unroll
        for (int mi = 0; mi < 2; ++mi) {
            int32x4 iv[4];
            iv[0] = __builtin_amdgcn_mfma_i32_16x16x64_i8(av[mi], bv[0], zero, 0, 0, 0);
            #pragma unroll
            for (int ni = 0; ni < 4; ++ni) {
                if (ni < 3)
                    iv[ni + 1] = __builtin_amdgcn_mfma_i32_16x16x64_i8(
                        av[mi], bv[ni + 1], zero, 0, 0, 0);
                f32x4 sab = sa[mi] * sb_s[ni];
                #pragma unroll
                for (int r = 0; r < 4; ++r)
                    acc[mi][ni][r] += (float)iv[ni][r] * sab[r];
                SB0();
            }
        }

        // ---- seal reads of buf[cb]; stage t+2 into it (overlaps half B) ----
        asm volatile("s_waitcnt lgkmcnt(0)" ::: "memory");
        FENCE(); __builtin_amdgcn_s_barrier(); FENCE();
        if (t + 2 < NTt) { stage(Ag, As[cb], t + 2); stage(Bg, Bs[cb], t + 2); }
        SB0();

        // ---- half B (mi=2,3) ----
        #pragma unroll
        for (int mi = 2; mi < 4; ++mi) {
            int32x4 iv[4];
            iv[0] = __builtin_amdgcn_mfma_i32_16x16x64_i8(av[mi], bv[0], zero, 0, 0, 0);
            #pragma unroll
            for (int ni = 0; ni < 4; ++ni) {
                if (ni < 3)
                    iv[ni + 1] = __builtin_amdgcn_mfma_i32_16x16x64_i8(
                        av[mi], bv[ni + 1], zero, 0, 0, 0);
                f32x4 sab = sa[mi] * sb_s[ni];
                #pragma unroll
                for (int r = 0; r < 4; ++r)
                    acc[mi][ni][r] += (float)iv[ni][r] * sab[r];
                SB0();
            }
        }

        FENCE(); __builtin_amdgcn_s_barrier(); FENCE();
    }

    // ---- epilogue: D map col = lane&15, row = (lane>>4)*4 + reg ----
    int cl = lane & 15;
    #pragma unroll
    for (int mi = 0; mi < 4; ++mi) {
        #pragma unroll
        for (int ni = 0; ni < 4; ++ni) {
            int row = rowA0 + wr * 64 + mi * 16 + rq;
            int col = colB0 + wc * 64 + ni * 16 + cl;
            float* cp = C + (size_t)row * N + col;
            #pragma unroll
            for (int r = 0; r < 4; ++r)
                cp[(size_t)r * N] = acc[mi][ni][r];
        }
    }
}

extern "C" void kernel_launch(void* const* d_in, const int* in_sizes, int n_in,
                              void* d_out, int out_size, void* d_ws, size_t ws_size,
                              hipStream_t stream) {
    const float* x = (const float*)d_in[0];
    const float* w = (const float*)d_in[1];
    float* out = (float*)d_out;

    const int K = 4096;
    const int T = in_sizes[0] / K;   // 8192
    const int O = in_sizes[1] / K;   // 4096

    // workspace layout (51 MB total)
    int8_t* qx  = (int8_t*)d_ws;                                  // T*K i8
    int8_t* qw  = qx + (size_t)T * K;                             // O*K i8
    float*  sxT = (float*)(qw + (size_t)O * K);                   // [K/64][T]
    float*  swT = sxT + (size_t)(K / 64) * T;                     // [K/64][O]

    quant_kernel<<<2048, 256, 0, stream>>>(x, qx, sxT, (T * K) >> 2, T);
    quant_kernel<<<2048, 256, 0, stream>>>(w, qw, swT, (O * K) >> 2, O);

    int nwg = (T / BM) * (O / BN);   // 64*32 = 2048
    gemm_kernel<<<nwg, 256, 0, stream>>>(qx, qw, sxT, swT, out, T, O, K);
}